// Round 13
// baseline (695.846 us; speedup 1.0000x reference)
//
#include <hip/hip_runtime.h>
#include <cmath>

// Problem constants (fixed by reference): B=8, N=2048, eps=0.01, 50 iters.
#define BATCH 8
#define NPT   2048
#define NPAIR (NPT / 2)               // 1024 column pairs
#define NPTS  (BATCH * NPT)
#define TILES 32                      // blocks per batch (64 rows each)
#define GRID_MAIN (BATCH * TILES)     // 256 blocks; ~83KB LDS -> 1 block/CU
#define THREADS 1024                  // 16 waves -> 4/SIMD
#define ITERS 50

// exp(v_j - 100*cost) = exp2( C_LOG2E*v_j + NEG100C*(n_i + n_j) + S200C*dot )
#define C_LOG2E 1.4426950408889634f
#define NEG100C (-144.26950408889634f)   // -100 * log2(e)
#define S200C   288.53900817779268f      //  200 * log2(e)
#define EPS_LOG 1e-8f
#define LN2_01  0.006931471805599453f    // 0.01 * ln(2)

typedef float v2f __attribute__((ext_vector_type(2)));
typedef float v4f __attribute__((ext_vector_type(4)));
typedef unsigned long long u64t;

static __device__ __forceinline__ float fast_exp2(float x) {
#if __has_builtin(__builtin_amdgcn_exp2f)
    return __builtin_amdgcn_exp2f(x);
#else
    return exp2f(x);
#endif
}

// Coherence-point (agent-scope, relaxed) accessors for cross-block data.
static __device__ __forceinline__ float gload(const float* p) {
    return __hip_atomic_load(p, __ATOMIC_RELAXED, __HIP_MEMORY_SCOPE_AGENT);
}
static __device__ __forceinline__ void gstore(float* p, float val) {
    __hip_atomic_store(p, val, __ATOMIC_RELAXED, __HIP_MEMORY_SCOPE_AGENT);
}
static __device__ __forceinline__ u64t gload2(const float* p) {   // 2 floats
    return __hip_atomic_load((const u64t*)p, __ATOMIC_RELAXED,
                             __HIP_MEMORY_SCOPE_AGENT);
}

// ---------------------------------------------------------------------------
__global__ void init_kernel(float* __restrict__ out,
                            unsigned int* __restrict__ flags) {
    int t = threadIdx.x;          // 256 threads
    if (t < BATCH) out[t] = 0.0f;
    flags[t] = 0u;                // BATCH*TILES = 256 flags
}

// ---------------------------------------------------------------------------
// Flag-array barrier — R8/R12-proven machinery (TILES=32-wide poll).
// ---------------------------------------------------------------------------
static __device__ __forceinline__ void flag_barrier(unsigned int* bflags,
                                                    int tile, int wave,
                                                    int lane,
                                                    unsigned int phase) {
    __syncthreads();
    if (wave == 0) {
        if (lane == 0)
            __hip_atomic_store(&bflags[tile], phase, __ATOMIC_RELAXED,
                               __HIP_MEMORY_SCOPE_AGENT);
        if (lane < TILES) {
            while (__hip_atomic_load(&bflags[lane], __ATOMIC_RELAXED,
                                     __HIP_MEMORY_SCOPE_AGENT) < phase) {
                __builtin_amdgcn_s_sleep(1);
            }
        }
    }
    __syncthreads();
    __builtin_amdgcn_sched_barrier(0);
}

// ---------------------------------------------------------------------------
// 4-rows-per-lane half-pass core: lane owns FOUR rows (rloc+16rr); each 32B
// pair fill (2 quarter-wave-uniform b128) feeds 8 exps -> LDS instruction
// count halved again vs R12 (512/CU/phase). Chunks interleaved (pair =
// wave*64 + 4s + ch) so the 4 addresses/instr occupy 16 distinct banks.
// ---------------------------------------------------------------------------
static __device__ __forceinline__ void half_core4(
        const v4f* cdXY, const v4f* cdZW, int p0,
        const v2f (&RX)[4], const v2f (&RY)[4],
        const v2f (&RZ)[4], const v2f (&RC)[4], float (&acc)[4])
{
    v2f a[4];
#pragma unroll
    for (int r = 0; r < 4; r++) a[r] = (v2f){0.0f, 0.0f};
#pragma unroll 4
    for (int s = 0; s < 16; s++) {
        v4f A = cdXY[p0 + 4 * s];                  // quarter-uniform b128
        v4f B = cdZW[p0 + 4 * s];                  // quarter-uniform b128
        v2f xx = __builtin_shufflevector(A, A, 0, 1);
        v2f yy = __builtin_shufflevector(A, A, 2, 3);
        v2f zz = __builtin_shufflevector(B, B, 0, 1);
        v2f ww = __builtin_shufflevector(B, B, 2, 3);
#pragma unroll
        for (int r = 0; r < 4; r++) {
            v2f t = xx * RX[r] + ww;               // compiler emits v_pk_fma
            t = yy * RY[r] + t;
            t = zz * RZ[r] + t;
            t = t + RC[r];
            a[r].x += fast_exp2(t.x);
            a[r].y += fast_exp2(t.y);
        }
    }
#pragma unroll
    for (int r = 0; r < 4; r++) acc[r] = a[r].x + a[r].y;
}

// ---------------------------------------------------------------------------
// Persistent kernel, 64 rows/block, 4 rows/lane.
// LDS = 64KB tiles + 17.4KB part -> 1 block/CU, 16 waves = 4/SIMD.
// Sync structure identical to R12 (best measured).
// ---------------------------------------------------------------------------
__global__ __launch_bounds__(THREADS, 4) void sinkhorn_kernel(
        const float* __restrict__ x1, const float* __restrict__ x2,
        float* __restrict__ u, float* __restrict__ v,
        unsigned int* __restrict__ flags, float* __restrict__ out)
{
    __shared__ v4f cd1XY[NPAIR], cd1ZW[NPAIR];   // side-1 cols (dual = u)
    __shared__ v4f cd2XY[NPAIR], cd2ZW[NPAIR];   // side-2 cols (dual = v)
    __shared__ __align__(16) float part[64][68]; // 16B-aligned rows, 17.4KB

    const int b    = blockIdx.x / TILES;
    const int tile = blockIdx.x % TILES;
    const int base = b * NPT;
    unsigned int* bflags = flags + b * TILES;

    const int tid  = threadIdx.x;
    const int wave = tid >> 6;
    const int lane = tid & 63;
    const int rloc = lane & 15;              // rows rloc, +16, +32, +48
    const int ch   = lane >> 4;              // column chunk 0..3 (interleaved)
    const int p0   = wave * 64 + ch;         // this lane's pair base

    const float log_mu = logf(1.0f / (float)NPT + EPS_LOG);   // == log_nu

    // ---- one-time staging: thread t stages pair t (both sides) ----
    float P1a, P1b, P2a, P2b;
    {
        const float* p = x1 + 3 * (base + 2 * tid);
        float ax = p[0], ay = p[1], az = p[2];
        float bx = p[3], by = p[4], bz = p[5];
        float na = fmaf(ax, ax, fmaf(ay, ay, az * az));
        float nb = fmaf(bx, bx, fmaf(by, by, bz * bz));
        P1a = na * NEG100C;  P1b = nb * NEG100C;
        cd1XY[tid] = (v4f){ax * S200C, bx * S200C, ay * S200C, by * S200C};
        cd1ZW[tid] = (v4f){az * S200C, bz * S200C, P1a, P1b};

        p = x2 + 3 * (base + 2 * tid);
        ax = p[0]; ay = p[1]; az = p[2];
        bx = p[3]; by = p[4]; bz = p[5];
        na = fmaf(ax, ax, fmaf(ay, ay, az * az));
        nb = fmaf(bx, bx, fmaf(by, by, bz * bz));
        P2a = na * NEG100C;  P2b = nb * NEG100C;
        cd2XY[tid] = (v4f){ax * S200C, bx * S200C, ay * S200C, by * S200C};
        cd2ZW[tid] = (v4f){az * S200C, bz * S200C, P2a, P2b};
    }

    // ---- lane's FOUR-row constants (splatted), both sides ----
    v2f RX1[4], RY1[4], RZ1[4], RC1[4], RX2[4], RY2[4], RZ2[4], RC2[4];
    float rc1s[4];
#pragma unroll
    for (int rr = 0; rr < 4; rr++) {
        int row = tile * 64 + rloc + 16 * rr;
        const float* p = x1 + 3 * (base + row);
        float a = p[0], bb = p[1], c = p[2];
        float nn = NEG100C * fmaf(a, a, fmaf(bb, bb, c * c));
        RX1[rr] = (v2f){a, a};  RY1[rr] = (v2f){bb, bb};
        RZ1[rr] = (v2f){c, c};  RC1[rr] = (v2f){nn, nn};
        rc1s[rr] = nn;
        p = x2 + 3 * (base + row);
        a = p[0]; bb = p[1]; c = p[2];
        nn = NEG100C * fmaf(a, a, fmaf(bb, bb, c * c));
        RX2[rr] = (v2f){a, a};  RY2[rr] = (v2f){bb, bb};
        RZ2[rr] = (v2f){c, c};  RC2[rr] = (v2f){nn, nn};
    }
    __syncthreads();

    // ---- helpers ----
    // Wave-self-contained fold: thread t refreshes w-slot of pair t (inside
    // its own wave's span [64w,64w+64)); same-wave LDS ordering, no barrier.
    auto fold2 = [&](v4f* ZW, const float* dual, float Pa, float Pb) {
        u64t d = gload2(dual + base + 2 * tid);
        reinterpret_cast<v2f*>(&ZW[tid])[1] = (v2f){
            fmaf(C_LOG2E, __uint_as_float((unsigned)d), Pa),
            fmaf(C_LOG2E, __uint_as_float((unsigned)(d >> 32)), Pb)};
    };
    auto do_phase = [&](const v4f* XY, const v4f* ZW,
                        const v2f (&RX)[4], const v2f (&RY)[4],
                        const v2f (&RZ)[4], const v2f (&RC)[4],
                        float* drow, unsigned int php) {
        float s4[4];
        half_core4(XY, ZW, p0, RX, RY, RZ, RC, s4);
#pragma unroll
        for (int r = 0; r < 4; r++) {            // combine 4 column chunks
            s4[r] += __shfl_xor(s4[r], 16, 64);
            s4[r] += __shfl_xor(s4[r], 32, 64);
        }
        if (lane < 16) {
#pragma unroll
            for (int r = 0; r < 4; r++) part[rloc + 16 * r][wave] = s4[r];
        }
        __syncthreads();
        if (wave == 0) {                          // lane = row 0..63
            const v4f* pr = reinterpret_cast<const v4f*>(&part[lane][0]);
            v4f q0 = pr[0], q1 = pr[1], q2 = pr[2], q3 = pr[3];
            float t = ((q0.x + q0.y) + (q0.z + q0.w)) +
                      ((q1.x + q1.y) + (q1.z + q1.w)) +
                      ((q2.x + q2.y) + (q2.z + q2.w)) +
                      ((q3.x + q3.y) + (q3.z + q3.w));
            gstore(drow + lane, log_mu - __logf(t + EPS_LOG));  // coalesced
        }
        flag_barrier(bflags, tile, wave, lane, php);
    };

    float* urow = u + base + tile * 64;
    float* vrow = v + base + tile * 64;

    // ---- 50 iterations, phases 1..100 (R12-proven schedule) ----
    do_phase(cd2XY, cd2ZW, RX1, RY1, RZ1, RC1, urow, 1);   // iter0 u (v=0)
    for (int it = 0; it < ITERS; it++) {
        fold2(cd1ZW, u, P1a, P1b);                         // fresh u -> side1 w
        do_phase(cd1XY, cd1ZW, RX2, RY2, RZ2, RC2, vrow, 2 * it + 2);
        if (it < ITERS - 1) {
            fold2(cd2ZW, v, P2a, P2b);                     // fresh v -> side2 w
            do_phase(cd2XY, cd2ZW, RX1, RY1, RZ1, RC1, urow, 2 * it + 3);
        }
    }

    // ---- fused EMD epilogue: emd[b] = sum_ij exp2(t) * cost,
    //      cost = 0.01*(u_i+v_j) - 0.01*ln2 * t  (algebraically exact) ----
    v2f* cvp = reinterpret_cast<v2f*>(cd1XY);   // wave-own-span reuse only
    {
        u64t d = gload2(v + base + 2 * tid);
        float a0 = __uint_as_float((unsigned)d);
        float b0 = __uint_as_float((unsigned)(d >> 32));
        reinterpret_cast<v2f*>(&cd2ZW[tid])[1] =
            (v2f){fmaf(C_LOG2E, a0, P2a), fmaf(C_LOG2E, b0, P2b)};
        cvp[tid] = (v2f){0.01f * a0, 0.01f * b0};
    }
    __syncthreads();

    v2f RCC[4], SU[4];
#pragma unroll
    for (int rr = 0; rr < 4; rr++) {
        float ur = gload(&u[base + tile * 64 + rloc + 16 * rr]);
        float rcs = fmaf(C_LOG2E, ur, rc1s[rr]);
        RCC[rr] = (v2f){rcs, rcs};
        float sus = 0.01f * ur;
        SU[rr] = (v2f){sus, sus};
    }

    const v2f NL2 = {-LN2_01, -LN2_01};
    v2f eacc = {0.0f, 0.0f};
#pragma unroll 4
    for (int s = 0; s < 16; s++) {
        v4f A   = cd2XY[p0 + 4 * s];
        v4f B   = cd2ZW[p0 + 4 * s];
        v2f cv2 = cvp[p0 + 4 * s];
        v2f xx = __builtin_shufflevector(A, A, 0, 1);
        v2f yy = __builtin_shufflevector(A, A, 2, 3);
        v2f zz = __builtin_shufflevector(B, B, 0, 1);
        v2f ww = __builtin_shufflevector(B, B, 2, 3);
#pragma unroll
        for (int r = 0; r < 4; r++) {
            v2f t = xx * RX1[r] + ww;
            t = yy * RY1[r] + t;
            t = zz * RZ1[r] + t;
            t = t + RCC[r];
            v2f c2 = t * NL2 + (SU[r] + cv2);
            eacc.x = fmaf(fast_exp2(t.x), c2.x, eacc.x);
            eacc.y = fmaf(fast_exp2(t.y), c2.y, eacc.y);
        }
    }
    float es = eacc.x + eacc.y;
#pragma unroll
    for (int m = 32; m >= 1; m >>= 1) es += __shfl_xor(es, m, 64);

    if (lane == 0) part[0][wave] = es;
    __syncthreads();
    if (tid == 0) {
        float s = 0.0f;
#pragma unroll
        for (int w = 0; w < 16; w++) s += part[0][w];
        atomicAdd(&out[b], s);
    }
}

// ---------------------------------------------------------------------------
extern "C" void kernel_launch(void* const* d_in, const int* in_sizes, int n_in,
                              void* d_out, int out_size, void* d_ws, size_t ws_size,
                              hipStream_t stream) {
    (void)in_sizes; (void)n_in; (void)out_size; (void)ws_size;
    const float* x1 = (const float*)d_in[0];
    const float* x2 = (const float*)d_in[1];
    float* out = (float*)d_out;

    char* ws = (char*)d_ws;
    float* u = (float*)ws;                             // NPTS floats
    float* v = u + NPTS;                               // NPTS floats
    unsigned int* flags = (unsigned int*)(v + NPTS);   // BATCH*TILES uints

    init_kernel<<<1, 256, 0, stream>>>(out, flags);
    sinkhorn_kernel<<<GRID_MAIN, THREADS, 0, stream>>>(x1, x2, u, v, flags, out);
}